// Round 2
// baseline (520.160 us; speedup 1.0000x reference)
//
#include <hip/hip_runtime.h>
#include <stdint.h>

// GraphConv (LightGCN-style) with exact JAX threefry dropout reproduction,
// using the PARTITIONABLE scheme (jax_threefry_partitionable=True, the
// default since JAX 0.4.30):
//   split(key, n):  subkey j = threefry(key, hi=0, lo=j)  (full output pair)
//   random_bits(key, 32, shape): elem i -> b1 ^ b2 of threefry(key, 0, i)
//
// Layout: d_out is [N_NODES][N_HOPS+1][D] f32; slice 0 = input embeds,
// slice h+1 = hop h output. Users (first 50000 nodes) then items — exactly
// the concatenation of the two reference outputs.

static constexpr int kUsers = 50000;
static constexpr int kItems = 100000;
static constexpr int kNodes = kUsers + kItems;   // 150000
static constexpr int kNnz   = 1000000;
static constexpr int kD     = 64;
static constexpr int kHops  = 3;
static constexpr int kRowF  = (kHops + 1) * kD;  // 256 floats per node row

// ---- JAX threefry2x32 (20 rounds), bit-exact -------------------------------
__host__ __device__ inline void tf2x32(uint32_t k0, uint32_t k1,
                                       uint32_t x0, uint32_t x1,
                                       uint32_t &o0, uint32_t &o1) {
  uint32_t ks2 = k0 ^ k1 ^ 0x1BD11BDAu;
  x0 += k0; x1 += k1;
#define TF_R(r) { x0 += x1; x1 = (x1 << (r)) | (x1 >> (32 - (r))); x1 ^= x0; }
  TF_R(13) TF_R(15) TF_R(26) TF_R(6)   x0 += k1;  x1 += ks2 + 1u;
  TF_R(17) TF_R(29) TF_R(16) TF_R(24)  x0 += ks2; x1 += k0 + 2u;
  TF_R(13) TF_R(15) TF_R(26) TF_R(6)   x0 += k0;  x1 += k1 + 3u;
  TF_R(17) TF_R(29) TF_R(16) TF_R(24)  x0 += k1;  x1 += ks2 + 4u;
  TF_R(13) TF_R(15) TF_R(26) TF_R(6)   x0 += ks2; x1 += k0 + 5u;
#undef TF_R
  o0 = x0; o1 = x1;
}

// partitionable random_bits, 32-bit: XOR-fold of the two output words,
// counter = 64-bit flat index as (hi, lo) = (0, i) for i < 2^32.
__device__ inline uint32_t jax_bits32(uint32_t k0, uint32_t k1, uint32_t i) {
  uint32_t b1, b2;
  tf2x32(k0, k1, 0u, i, b1, b2);
  return b1 ^ b2;
}

// jax.random.uniform bit manipulation: [1,2) mantissa trick, minus 1.
__device__ inline float bits_to_unit(uint32_t b) {
  return __uint_as_float((b >> 9) | 0x3f800000u) - 1.0f;
}

// ---- kernel 1: slice0 = concat(user,item); slices 1..3 = 0 -----------------
__global__ __launch_bounds__(256) void init_kernel(
    const float4* __restrict__ user, const float4* __restrict__ item,
    float4* __restrict__ out) {
  int i = blockIdx.x * 256 + threadIdx.x;          // over kNodes*16 float4s
  if (i >= kNodes * 16) return;
  int node = i >> 4, q = i & 15;
  float4 v = (node < kUsers) ? user[node * 16 + q]
                             : item[(node - kUsers) * 16 + q];
  float4 z = make_float4(0.f, 0.f, 0.f, 0.f);
  float4* row = out + (size_t)node * (kRowF / 4);  // 64 float4 per node
  row[q]      = v;
  row[16 + q] = z;
  row[32 + q] = z;
  row[48 + q] = z;
}

// ---- kernel 2: SpMM with fused edge dropout. One wave (64 lanes) per edge.
__global__ __launch_bounds__(256) void spmm_kernel(
    const int* __restrict__ rows, const int* __restrict__ cols,
    const float* __restrict__ vals, float* __restrict__ out, int hop,
    uint32_t k0, uint32_t k1) {
  int e = (int)((blockIdx.x * 256u + threadIdx.x) >> 6);
  if (e >= kNnz) return;
  int lane = threadIdx.x & 63;

  // wave-uniform edge dropout bit (all 64 lanes compute the same value)
  float u = bits_to_unit(jax_bits32(k0, k1, (uint32_t)e));
  if (!(0.5f + u >= 1.0f)) return;                 // keep iff floor(0.5+u)==1

  float v = vals[e] * 2.0f;                        // 1/(1-0.5) scale
  int r = rows[e], c = cols[e];
  float msg = v * out[(size_t)c * kRowF + hop * kD + lane];
  atomicAdd(&out[(size_t)r * kRowF + (hop + 1) * kD + lane], msg);
}

// ---- kernel 3: message dropout in place on slice hop+1 ---------------------
__global__ __launch_bounds__(256) void mdrop_kernel(
    float* __restrict__ out, int hop, uint32_t k0, uint32_t k1) {
  const int total = kNodes * kD;                   // 9,600,000
  int j = blockIdx.x * 256 + threadIdx.x;
  if (j >= total) return;
  float u = bits_to_unit(jax_bits32(k0, k1, (uint32_t)j));
  int node = j >> 6, d = j & 63;
  size_t idx = (size_t)node * kRowF + (hop + 1) * kD + d;
  float a = out[idx];
  out[idx] = (u < 0.9f) ? a / 0.9f : 0.0f;
}

extern "C" void kernel_launch(void* const* d_in, const int* in_sizes, int n_in,
                              void* d_out, int out_size, void* d_ws, size_t ws_size,
                              hipStream_t stream) {
  const float* user = (const float*)d_in[0];
  const float* item = (const float*)d_in[1];
  const int*   rows = (const int*)d_in[2];
  const int*   cols = (const int*)d_in[3];
  const float* vals = (const float*)d_in[4];
  float* out = (float*)d_out;

  init_kernel<<<(kNodes * 16 + 255) / 256, 256, 0, stream>>>(
      (const float4*)user, (const float4*)item, (float4*)out);

  // Host-side key schedule (pure CPU, deterministic, graph-capture safe).
  // Partitionable split: subkey j = threefry(key, 0, j), full output pair.
  uint32_t k0 = 0u, k1 = 42u;                      // jax.random.key(42)
  for (int hop = 0; hop < kHops; ++hop) {
    uint32_t n0, n1, e0, e1, m0, m1;
    tf2x32(k0, k1, 0u, 0u, n0, n1);                // keys[0] -> next key
    tf2x32(k0, k1, 0u, 1u, e0, e1);                // keys[1] -> edge dropout
    tf2x32(k0, k1, 0u, 2u, m0, m1);                // keys[2] -> message dropout

    spmm_kernel<<<(kNnz * 64 + 255) / 256, 256, 0, stream>>>(
        rows, cols, vals, out, hop, e0, e1);
    mdrop_kernel<<<(kNodes * kD + 255) / 256, 256, 0, stream>>>(
        out, hop, m0, m1);

    k0 = n0; k1 = n1;
  }
}